// Round 1
// baseline (6335.988 us; speedup 1.0000x reference)
//
#include <hip/hip_runtime.h>
#include <math.h>

#define HC 32      // H*C
#define CH 16      // channels per head
#define NSLOPE 0.2f

// ---- order-preserving float<->uint encoding for atomicMax on signed floats ----
__device__ __forceinline__ unsigned fenc(float x){
    int i = __float_as_int(x);
    return (i >= 0) ? (unsigned(i) | 0x80000000u) : ~unsigned(i);
}
__device__ __forceinline__ float fdec(unsigned u){
    int i = (u & 0x80000000u) ? int(u & 0x7fffffffu) : int(~u);
    return __int_as_float(i);
}

__global__ void k_deg(const int* __restrict__ ei, float* __restrict__ deg, int E){
    int e = blockIdx.x*blockDim.x + threadIdx.x;
    if (e >= E) return;
    atomicAdd(&deg[ei[e]],   1.0f);
    atomicAdd(&deg[ei[E+e]], 1.0f);
}

// layer-1 xl/xr from features [1, deg, rand]
__global__ void k_feat1(const float* __restrict__ deg, const float* __restrict__ rnd,
                        const float* __restrict__ Wl, const float* __restrict__ bl,
                        const float* __restrict__ Wr, const float* __restrict__ br,
                        float* __restrict__ A, float* __restrict__ B, int N){
    int idx = blockIdx.x*blockDim.x + threadIdx.x;
    if (idx >= N*HC) return;
    int n = idx >> 5, k = idx & 31;
    float f1 = deg[n], f2 = rnd[n];
    A[idx] = Wl[k*3] + Wl[k*3+1]*f1 + Wl[k*3+2]*f2 + bl[k];
    B[idx] = Wr[k*3] + Wr[k*3+1]*f1 + Wr[k*3+2]*f2 + br[k];
}

// layer-2 xl/xr: two 32x32 linears sharing the x row
__global__ void k_lin2(const float* __restrict__ X,
                       const float* __restrict__ Wl, const float* __restrict__ bl,
                       const float* __restrict__ Wr, const float* __restrict__ br,
                       float* __restrict__ A, float* __restrict__ B, int N){
    int idx = blockIdx.x*blockDim.x + threadIdx.x;
    if (idx >= N*HC) return;
    int n = idx >> 5, k = idx & 31;
    const float* x  = X  + n*HC;
    const float* wl = Wl + k*HC;
    const float* wr = Wr + k*HC;
    float a = bl[k], b = br[k];
    #pragma unroll
    for (int j = 0; j < HC; ++j){ float xv = x[j]; a += xv*wl[j]; b += xv*wr[j]; }
    A[idx] = a; B[idx] = b;
}

// per-(edge,head) attention score + segment max via encoded atomicMax
__global__ void k_score(const int* __restrict__ ei, int E, int EP,
                        const float* __restrict__ A, const float* __restrict__ B,
                        const float* __restrict__ att,
                        float* __restrict__ score, unsigned* __restrict__ smax){
    int idx = blockIdx.x*blockDim.x + threadIdx.x;
    if (idx >= EP*2) return;
    int e = idx >> 1, h = idx & 1;
    int s, d;
    if (e < E){ s = ei[e]; d = ei[E+e]; } else { s = e - E; d = s; }
    const float* ar = A + s*HC + h*CH;
    const float* br = B + d*HC + h*CH;
    const float* at = att + h*CH;
    float sc = 0.f;
    #pragma unroll
    for (int c = 0; c < CH; ++c){
        float m = ar[c] + br[c];
        m = (m > 0.f) ? m : NSLOPE*m;
        sc += m * at[c];
    }
    score[idx] = sc;
    atomicMax(&smax[d*2 + h], fenc(sc));
}

// per-(edge,head): ex = exp(score - max); denom += ex; acc[d] += ex * xl[s]
// (normalization deferred to k_norm: alpha = ex/denom is per-dst)
__global__ void k_accum(const int* __restrict__ ei, int E, int EP,
                        const float* __restrict__ A,
                        const float* __restrict__ score, const unsigned* __restrict__ smax,
                        float* __restrict__ denom, float* __restrict__ acc){
    int idx = blockIdx.x*blockDim.x + threadIdx.x;
    if (idx >= EP*2) return;
    int e = idx >> 1, h = idx & 1;
    int s, d;
    if (e < E){ s = ei[e]; d = ei[E+e]; } else { s = e - E; d = s; }
    float ex = expf(score[idx] - fdec(smax[d*2 + h]));
    atomicAdd(&denom[d*2 + h], ex);
    const float* ar = A + s*HC + h*CH;
    float* o = acc + d*HC + h*CH;
    #pragma unroll
    for (int c = 0; c < CH; ++c) atomicAdd(&o[c], ex * ar[c]);
}

// x = ELU(acc/denom + bias)
__global__ void k_norm(const float* __restrict__ acc, const float* __restrict__ denom,
                       const float* __restrict__ bias, float* __restrict__ X, int N){
    int idx = blockIdx.x*blockDim.x + threadIdx.x;
    if (idx >= N*HC) return;
    int n = idx >> 5, k = idx & 31, h = k >> 4;
    float v = acc[idx] / (denom[n*2 + h] + 1e-16f) + bias[k];
    X[idx] = (v > 0.f) ? v : expm1f(v);
}

__global__ void k_pool(const float* __restrict__ X, const int* __restrict__ batch,
                       float* __restrict__ pool, float* __restrict__ cnt, int N){
    int idx = blockIdx.x*blockDim.x + threadIdx.x;
    if (idx >= N*HC) return;
    int n = idx >> 5, k = idx & 31;
    int g = batch[n];
    atomicAdd(&pool[g*HC + k], X[idx]);
    if (k == 0) atomicAdd(&cnt[g], 1.0f);
}

__global__ void k_final(const float* __restrict__ pool, const float* __restrict__ cnt,
                        const float* __restrict__ Wfc, const float* __restrict__ bfc,
                        float* __restrict__ out, int G){
    int g = blockIdx.x*blockDim.x + threadIdx.x;
    if (g >= G) return;
    float c = cnt[g]; c = (c < 1.f) ? 1.f : c;
    const float* p = pool + g*HC;
    float l0 = bfc[0], l1 = bfc[1];
    #pragma unroll
    for (int j = 0; j < HC; ++j){
        float pv = p[j] / c;
        l0 += pv * Wfc[j];
        l1 += pv * Wfc[HC + j];
    }
    float m = (l0 > l1) ? l0 : l1;
    float lse = m + logf(expf(l0 - m) + expf(l1 - m));
    out[g*2 + 0] = l0 - lse;
    out[g*2 + 1] = l1 - lse;
}

extern "C" void kernel_launch(void* const* d_in, const int* in_sizes, int n_in,
                              void* d_out, int out_size, void* d_ws, size_t ws_size,
                              hipStream_t stream) {
    const int*   ei    = (const int*)  d_in[0];
    const int*   batch = (const int*)  d_in[1];
    const float* rnd   = (const float*)d_in[2];
    const float* W1l   = (const float*)d_in[3];
    const float* b1l   = (const float*)d_in[4];
    const float* W1r   = (const float*)d_in[5];
    const float* b1r   = (const float*)d_in[6];
    const float* att1  = (const float*)d_in[7];
    const float* bias1 = (const float*)d_in[8];
    const float* W2l   = (const float*)d_in[9];
    const float* b2l   = (const float*)d_in[10];
    const float* W2r   = (const float*)d_in[11];
    const float* b2r   = (const float*)d_in[12];
    const float* att2  = (const float*)d_in[13];
    const float* bias2 = (const float*)d_in[14];
    const float* Wfc   = (const float*)d_in[15];
    const float* bfc   = (const float*)d_in[16];

    const int E  = in_sizes[0] / 2;
    const int N  = in_sizes[1];
    const int G  = out_size / 2;
    const int EP = E + N;   // edges incl. self-loops

    // workspace layout (floats): deg | A | B | X | acc | smax(u32) | denom | score | pool | cnt
    float* ws    = (float*)d_ws;
    float* deg   = ws;
    float* A     = deg + N;
    float* B     = A + (size_t)N*HC;
    float* X     = B + (size_t)N*HC;
    float* acc   = X + (size_t)N*HC;
    unsigned* smax = (unsigned*)(acc + (size_t)N*HC);
    float* denom = (float*)smax + (size_t)N*2;
    float* score = denom + (size_t)N*2;
    float* pool  = score + (size_t)EP*2;
    float* cnt   = pool + (size_t)G*HC;

    const int T = 256;
    const int gNK = (N*HC + T-1)/T;
    const int gEH = (EP*2 + T-1)/T;

    // zero accumulators (ws is poisoned 0xAA before every call)
    hipMemsetAsync(deg, 0, (size_t)N*sizeof(float), stream);
    hipMemsetAsync(acc, 0, (size_t)(N*HC + N*2 + N*2)*sizeof(float), stream); // acc+smax+denom
    hipMemsetAsync(pool, 0, (size_t)(G*HC + G)*sizeof(float), stream);        // pool+cnt

    // ---- features ----
    k_deg  <<<(E + T-1)/T, T, 0, stream>>>(ei, deg, E);
    k_feat1<<<gNK, T, 0, stream>>>(deg, rnd, W1l, b1l, W1r, b1r, A, B, N);

    // ---- layer 1 ----
    k_score<<<gEH, T, 0, stream>>>(ei, E, EP, A, B, att1, score, smax);
    k_accum<<<gEH, T, 0, stream>>>(ei, E, EP, A, score, smax, denom, acc);
    k_norm <<<gNK, T, 0, stream>>>(acc, denom, bias1, X, N);

    // ---- layer 2 ----
    hipMemsetAsync(acc, 0, (size_t)(N*HC + N*2 + N*2)*sizeof(float), stream);
    k_lin2 <<<gNK, T, 0, stream>>>(X, W2l, b2l, W2r, b2r, A, B, N);
    k_score<<<gEH, T, 0, stream>>>(ei, E, EP, A, B, att2, score, smax);
    k_accum<<<gEH, T, 0, stream>>>(ei, E, EP, A, score, smax, denom, acc);
    k_norm <<<gNK, T, 0, stream>>>(acc, denom, bias2, X, N);

    // ---- pool + classifier ----
    k_pool <<<gNK, T, 0, stream>>>(X, batch, pool, cnt, N);
    k_final<<<(G + T-1)/T, T, 0, stream>>>(pool, cnt, Wfc, bfc, (float*)d_out, G);
}

// Round 2
// 798.654 us; speedup vs baseline: 7.9333x; 7.9333x over previous
//
#include <hip/hip_runtime.h>
#include <math.h>

#define HC 32      // H*C
#define CH 16      // channels per head
#define NSLOPE 0.2f
#define NEG_BIG -1e30f

__global__ void k_deg(const int* __restrict__ ei, float* __restrict__ deg, int E){
    int e = blockIdx.x*blockDim.x + threadIdx.x;
    if (e >= E) return;
    atomicAdd(&deg[ei[e]],   1.0f);
    atomicAdd(&deg[ei[E+e]], 1.0f);
}

// layer-1 xl/xr from features [1, deg, rand]
__global__ void k_feat1(const float* __restrict__ deg, const float* __restrict__ rnd,
                        const float* __restrict__ Wl, const float* __restrict__ bl,
                        const float* __restrict__ Wr, const float* __restrict__ br,
                        float* __restrict__ A, float* __restrict__ B, int N){
    int idx = blockIdx.x*blockDim.x + threadIdx.x;
    if (idx >= N*HC) return;
    int n = idx >> 5, k = idx & 31;
    float f1 = deg[n], f2 = rnd[n];
    A[idx] = Wl[k*3] + Wl[k*3+1]*f1 + Wl[k*3+2]*f2 + bl[k];
    B[idx] = Wr[k*3] + Wr[k*3+1]*f1 + Wr[k*3+2]*f2 + br[k];
}

// layer-2 xl/xr: two 32x32 linears sharing the x row
__global__ void k_lin2(const float* __restrict__ X,
                       const float* __restrict__ Wl, const float* __restrict__ bl,
                       const float* __restrict__ Wr, const float* __restrict__ br,
                       float* __restrict__ A, float* __restrict__ B, int N){
    int idx = blockIdx.x*blockDim.x + threadIdx.x;
    if (idx >= N*HC) return;
    int n = idx >> 5, k = idx & 31;
    const float* x  = X  + n*HC;
    const float* wl = Wl + k*HC;
    const float* wr = Wr + k*HC;
    float a = bl[k], b = br[k];
    #pragma unroll
    for (int j = 0; j < HC; ++j){ float xv = x[j]; a += xv*wl[j]; b += xv*wr[j]; }
    A[idx] = a; B[idx] = b;
}

// ---------------- CSR-by-dst build (self-loops included) ----------------
__global__ void k_count(const int* __restrict__ ei, int E, int EP, int* __restrict__ cntd){
    int e = blockIdx.x*blockDim.x + threadIdx.x;
    if (e >= EP) return;
    int d = (e < E) ? ei[E+e] : (e - E);
    atomicAdd(&cntd[d], 1);
}

// single-block exclusive scan over N counts -> rs[0..N]
__global__ void k_scan(const int* __restrict__ cntd, int* __restrict__ rs, int N){
    __shared__ int part[1024];
    int t = threadIdx.x;
    int chunk = (N + 1023) >> 10;
    int beg = t*chunk, end = beg + chunk;
    if (beg > N) beg = N;
    if (end > N) end = N;
    int s = 0;
    for (int i = beg; i < end; ++i) s += cntd[i];
    part[t] = s;
    __syncthreads();
    for (int d = 1; d < 1024; d <<= 1){
        int v = (t >= d) ? part[t-d] : 0;
        __syncthreads();
        part[t] += v;
        __syncthreads();
    }
    int off = part[t] - s;   // exclusive prefix
    for (int i = beg; i < end; ++i){ rs[i] = off; off += cntd[i]; }
    if (t == 1023) rs[N] = part[1023];
}

__global__ void k_scatter(const int* __restrict__ ei, int E, int EP,
                          const int* __restrict__ rs, int* __restrict__ cursor,
                          int* __restrict__ col){
    int e = blockIdx.x*blockDim.x + threadIdx.x;
    if (e >= EP) return;
    int s, d;
    if (e < E){ s = ei[e]; d = ei[E+e]; } else { s = e - E; d = s; }
    int pos = rs[d] + atomicAdd(&cursor[d], 1);
    col[pos] = s;
}

// ---------------- fused GATv2 layer: score + online softmax + aggregate + bias + ELU ----
// one 16-lane subgroup per (dst, head); no atomics, no score buffer.
__global__ void k_gat(const int* __restrict__ rs, const int* __restrict__ col,
                      const float* __restrict__ A, const float* __restrict__ B,
                      const float* __restrict__ att, const float* __restrict__ bias,
                      float* __restrict__ X, int N){
    int sg = blockIdx.x*(blockDim.x >> 4) + (threadIdx.x >> 4);
    int r  = threadIdx.x & 15;
    if (sg >= N*2) return;
    int d = sg >> 1, h = sg & 1;

    float xr[CH], at[CH];
    #pragma unroll
    for (int c = 0; c < CH; ++c){
        xr[c] = B[d*HC + h*CH + c];
        at[c] = att[h*CH + c];
    }

    float m = NEG_BIG, l = 0.f;
    float acc[CH];
    #pragma unroll
    for (int c = 0; c < CH; ++c) acc[c] = 0.f;

    int beg = rs[d], end = rs[d+1];
    for (int p = beg + r; p < end; p += 16){
        int s = col[p];
        const float* xl = A + s*HC + h*CH;
        float x[CH];
        #pragma unroll
        for (int c = 0; c < CH; ++c) x[c] = xl[c];
        float sc = 0.f;
        #pragma unroll
        for (int c = 0; c < CH; ++c){
            float mm = x[c] + xr[c];
            mm = (mm > 0.f) ? mm : NSLOPE*mm;
            sc += mm * at[c];
        }
        float nm = fmaxf(m, sc);
        float a  = __expf(m - nm);
        float p2 = __expf(sc - nm);
        l = l*a + p2;
        #pragma unroll
        for (int c = 0; c < CH; ++c) acc[c] = acc[c]*a + p2*x[c];
        m = nm;
    }

    // merge (m,l,acc[16]) across the 16-lane subgroup
    #pragma unroll
    for (int off = 8; off >= 1; off >>= 1){
        float m2 = __shfl_xor(m, off);
        float l2 = __shfl_xor(l, off);
        float nm = fmaxf(m, m2);
        float a  = __expf(m  - nm);
        float b  = __expf(m2 - nm);
        l = l*a + l2*b;
        #pragma unroll
        for (int c = 0; c < CH; ++c)
            acc[c] = acc[c]*a + __shfl_xor(acc[c], off)*b;
        m = nm;
    }

    if (r == 0){
        float* o = X + d*HC + h*CH;
        #pragma unroll
        for (int c = 0; c < CH; ++c){
            float v = acc[c]/(l + 1e-16f) + bias[h*CH + c];
            o[c] = (v > 0.f) ? v : expm1f(v);
        }
    }
}

__global__ void k_pool(const float* __restrict__ X, const int* __restrict__ batch,
                       float* __restrict__ pool, float* __restrict__ cnt, int N){
    int idx = blockIdx.x*blockDim.x + threadIdx.x;
    if (idx >= N*HC) return;
    int n = idx >> 5, k = idx & 31;
    int g = batch[n];
    atomicAdd(&pool[g*HC + k], X[idx]);
    if (k == 0) atomicAdd(&cnt[g], 1.0f);
}

__global__ void k_final(const float* __restrict__ pool, const float* __restrict__ cnt,
                        const float* __restrict__ Wfc, const float* __restrict__ bfc,
                        float* __restrict__ out, int G){
    int g = blockIdx.x*blockDim.x + threadIdx.x;
    if (g >= G) return;
    float c = cnt[g]; c = (c < 1.f) ? 1.f : c;
    const float* p = pool + g*HC;
    float l0 = bfc[0], l1 = bfc[1];
    #pragma unroll
    for (int j = 0; j < HC; ++j){
        float pv = p[j] / c;
        l0 += pv * Wfc[j];
        l1 += pv * Wfc[HC + j];
    }
    float m = (l0 > l1) ? l0 : l1;
    float lse = m + logf(expf(l0 - m) + expf(l1 - m));
    out[g*2 + 0] = l0 - lse;
    out[g*2 + 1] = l1 - lse;
}

extern "C" void kernel_launch(void* const* d_in, const int* in_sizes, int n_in,
                              void* d_out, int out_size, void* d_ws, size_t ws_size,
                              hipStream_t stream) {
    const int*   ei    = (const int*)  d_in[0];
    const int*   batch = (const int*)  d_in[1];
    const float* rnd   = (const float*)d_in[2];
    const float* W1l   = (const float*)d_in[3];
    const float* b1l   = (const float*)d_in[4];
    const float* W1r   = (const float*)d_in[5];
    const float* b1r   = (const float*)d_in[6];
    const float* att1  = (const float*)d_in[7];
    const float* bias1 = (const float*)d_in[8];
    const float* W2l   = (const float*)d_in[9];
    const float* b2l   = (const float*)d_in[10];
    const float* W2r   = (const float*)d_in[11];
    const float* b2r   = (const float*)d_in[12];
    const float* att2  = (const float*)d_in[13];
    const float* bias2 = (const float*)d_in[14];
    const float* Wfc   = (const float*)d_in[15];
    const float* bfc   = (const float*)d_in[16];

    const int E  = in_sizes[0] / 2;
    const int N  = in_sizes[1];
    const int G  = out_size / 2;
    const int EP = E + N;   // edges incl. self-loops

    // workspace layout
    float* ws    = (float*)d_ws;
    float* deg   = ws;                        // N
    float* A     = deg + N;                   // N*HC
    float* B     = A + (size_t)N*HC;          // N*HC
    float* X     = B + (size_t)N*HC;          // N*HC
    float* pool  = X + (size_t)N*HC;          // G*HC
    float* cnt   = pool + (size_t)G*HC;       // G
    int*   cntd  = (int*)(cnt + G);           // N
    int*   rsofs = cntd + N;                  // N+1
    int*   curs  = rsofs + N + 1;             // N
    int*   col   = curs + N;                  // EP

    const int T = 256;
    const int gNK = (N*HC + T-1)/T;
    const int gEP = (EP + T-1)/T;
    const int gSG = (N*2 + (T>>4) - 1)/(T>>4);   // 16 subgroups per 256-block

    // zero accumulators (ws is poisoned 0xAA before every call)
    hipMemsetAsync(deg,  0, (size_t)N*sizeof(float), stream);
    hipMemsetAsync(pool, 0, (size_t)(G*HC + G)*sizeof(float), stream);
    hipMemsetAsync(cntd, 0, (size_t)N*sizeof(int), stream);
    hipMemsetAsync(curs, 0, (size_t)N*sizeof(int), stream);

    // ---- features + CSR build (CSR shared by both layers) ----
    k_deg    <<<(E + T-1)/T, T, 0, stream>>>(ei, deg, E);
    k_feat1  <<<gNK, T, 0, stream>>>(deg, rnd, W1l, b1l, W1r, b1r, A, B, N);
    k_count  <<<gEP, T, 0, stream>>>(ei, E, EP, cntd);
    k_scan   <<<1, 1024, 0, stream>>>(cntd, rsofs, N);
    k_scatter<<<gEP, T, 0, stream>>>(ei, E, EP, rsofs, curs, col);

    // ---- layer 1 (fused score+softmax+aggregate+bias+ELU) ----
    k_gat<<<gSG, T, 0, stream>>>(rsofs, col, A, B, att1, bias1, X, N);

    // ---- layer 2 ----
    k_lin2<<<gNK, T, 0, stream>>>(X, W2l, b2l, W2r, b2r, A, B, N);
    k_gat <<<gSG, T, 0, stream>>>(rsofs, col, A, B, att2, bias2, X, N);

    // ---- pool + classifier ----
    k_pool <<<gNK, T, 0, stream>>>(X, batch, pool, cnt, N);
    k_final<<<(G + T-1)/T, T, 0, stream>>>(pool, cnt, Wfc, bfc, (float*)d_out, G);
}

// Round 3
// 650.982 us; speedup vs baseline: 9.7330x; 1.2268x over previous
//
#include <hip/hip_runtime.h>
#include <math.h>

#define HC 32      // H*C
#define CH 16      // channels per head
#define NSLOPE 0.2f
#define NEG_BIG -1e30f

// packed per-node counters: low 16 = src count, high 16 = dst count
__global__ void k_hist(const int* __restrict__ ei, unsigned* __restrict__ hist, int E){
    int e = blockIdx.x*blockDim.x + threadIdx.x;
    if (e >= E) return;
    atomicAdd(&hist[ei[e]],   1u);
    atomicAdd(&hist[ei[E+e]], 1u << 16);
}

// layer-1 xl/xr from features [1, deg, rand]; deg = lo+hi of hist
__global__ void k_feat1(const unsigned* __restrict__ hist, const float* __restrict__ rnd,
                        const float* __restrict__ Wl, const float* __restrict__ bl,
                        const float* __restrict__ Wr, const float* __restrict__ br,
                        float* __restrict__ A, float* __restrict__ B, int N){
    int idx = blockIdx.x*blockDim.x + threadIdx.x;
    if (idx >= N*HC) return;
    int n = idx >> 5, k = idx & 31;
    unsigned h = hist[n];
    float f1 = (float)((h & 0xffffu) + (h >> 16));
    float f2 = rnd[n];
    A[idx] = Wl[k*3] + Wl[k*3+1]*f1 + Wl[k*3+2]*f2 + bl[k];
    B[idx] = Wr[k*3] + Wr[k*3+1]*f1 + Wr[k*3+2]*f2 + br[k];
}

// layer-2 xl/xr: two 32x32 linears sharing the x row
__global__ void k_lin2(const float* __restrict__ X,
                       const float* __restrict__ Wl, const float* __restrict__ bl,
                       const float* __restrict__ Wr, const float* __restrict__ br,
                       float* __restrict__ A, float* __restrict__ B, int N){
    int idx = blockIdx.x*blockDim.x + threadIdx.x;
    if (idx >= N*HC) return;
    int n = idx >> 5, k = idx & 31;
    const float* x  = X  + n*HC;
    const float* wl = Wl + k*HC;
    const float* wr = Wr + k*HC;
    float a = bl[k], b = br[k];
    #pragma unroll
    for (int j = 0; j < HC; ++j){ float xv = x[j]; a += xv*wl[j]; b += xv*wr[j]; }
    A[idx] = a; B[idx] = b;
}

// single-block exclusive scan: row starts rs[0..N]; per-dst count = (hist>>16)+1 (self-loop)
__global__ void k_scan(const unsigned* __restrict__ hist, int* __restrict__ rs, int N){
    __shared__ int part[1024];
    int t = threadIdx.x;
    int chunk = (N + 1023) >> 10;
    int beg = t*chunk, end = beg + chunk;
    if (beg > N) beg = N;
    if (end > N) end = N;
    int s = 0;
    for (int i = beg; i < end; ++i) s += (int)(hist[i] >> 16) + 1;
    part[t] = s;
    __syncthreads();
    for (int d = 1; d < 1024; d <<= 1){
        int v = (t >= d) ? part[t-d] : 0;
        __syncthreads();
        part[t] += v;
        __syncthreads();
    }
    int off = part[t] - s;   // exclusive prefix
    for (int i = beg; i < end; ++i){ rs[i] = off; off += (int)(hist[i] >> 16) + 1; }
    if (t == 1023) rs[N] = part[1023];
}

// curs was memcpy'd from rs; atomicAdd returns the slot directly
__global__ void k_scatter(const int* __restrict__ ei, int E, int EP,
                          int* __restrict__ curs, int* __restrict__ col){
    int e = blockIdx.x*blockDim.x + threadIdx.x;
    if (e >= EP) return;
    int s, d;
    if (e < E){ s = ei[e]; d = ei[E+e]; } else { s = e - E; d = s; }
    int pos = atomicAdd(&curs[d], 1);
    col[pos] = s;
}

// fused GATv2 layer: score + online softmax + aggregate + bias + ELU
// one 16-lane subgroup per (dst, head); no atomics, no score buffer.
__global__ void k_gat(const int* __restrict__ rs, const int* __restrict__ col,
                      const float* __restrict__ A, const float* __restrict__ B,
                      const float* __restrict__ att, const float* __restrict__ bias,
                      float* __restrict__ X, int N){
    int sg = blockIdx.x*(blockDim.x >> 4) + (threadIdx.x >> 4);
    int r  = threadIdx.x & 15;
    if (sg >= N*2) return;
    int d = sg >> 1, h = sg & 1;

    float xr[CH], at[CH];
    #pragma unroll
    for (int c = 0; c < CH; ++c){
        xr[c] = B[d*HC + h*CH + c];
        at[c] = att[h*CH + c];
    }

    float m = NEG_BIG, l = 0.f;
    float acc[CH];
    #pragma unroll
    for (int c = 0; c < CH; ++c) acc[c] = 0.f;

    int beg = rs[d], end = rs[d+1];
    for (int p = beg + r; p < end; p += 16){
        int s = col[p];
        const float* xl = A + s*HC + h*CH;
        float x[CH];
        #pragma unroll
        for (int c = 0; c < CH; ++c) x[c] = xl[c];
        float sc = 0.f;
        #pragma unroll
        for (int c = 0; c < CH; ++c){
            float mm = x[c] + xr[c];
            mm = (mm > 0.f) ? mm : NSLOPE*mm;
            sc += mm * at[c];
        }
        float nm = fmaxf(m, sc);
        float a  = __expf(m - nm);
        float p2 = __expf(sc - nm);
        l = l*a + p2;
        #pragma unroll
        for (int c = 0; c < CH; ++c) acc[c] = acc[c]*a + p2*x[c];
        m = nm;
    }

    // merge (m,l,acc[16]) across the 16-lane subgroup
    #pragma unroll
    for (int off = 8; off >= 1; off >>= 1){
        float m2 = __shfl_xor(m, off);
        float l2 = __shfl_xor(l, off);
        float nm = fmaxf(m, m2);
        float a  = __expf(m  - nm);
        float b  = __expf(m2 - nm);
        l = l*a + l2*b;
        #pragma unroll
        for (int c = 0; c < CH; ++c)
            acc[c] = acc[c]*a + __shfl_xor(acc[c], off)*b;
        m = nm;
    }

    if (r == 0){
        float* o = X + d*HC + h*CH;
        #pragma unroll
        for (int c = 0; c < CH; ++c){
            float v = acc[c]/(l + 1e-16f) + bias[h*CH + c];
            o[c] = (v > 0.f) ? v : expm1f(v);
        }
    }
}

// batch is sorted: graph g's nodes are [gb[g], gb[g+1])
__global__ void k_bounds(const int* __restrict__ batch, int* __restrict__ gb, int N, int G){
    int g = blockIdx.x*blockDim.x + threadIdx.x;
    if (g > G) return;
    int lo = 0, hi = N;
    while (lo < hi){
        int mid = (lo + hi) >> 1;
        if (batch[mid] < g) lo = mid + 1; else hi = mid;
    }
    gb[g] = lo;
}

// fused mean-pool + fc + log_softmax: one 64-lane wave per graph, no atomics
__global__ void k_poolfc(const float* __restrict__ X, const int* __restrict__ gb,
                         const float* __restrict__ Wfc, const float* __restrict__ bfc,
                         float* __restrict__ out, int G){
    int g = blockIdx.x;
    int lane = threadIdx.x;          // 64
    int c = lane & 31, half = lane >> 5;
    int beg = gb[g], end = gb[g+1];
    float s = 0.f;
    for (int n = beg + half; n < end; n += 2) s += X[n*HC + c];
    s += __shfl_xor(s, 32);          // channel sum now in all lanes with this c
    float cntf = (float)(end - beg);
    if (cntf < 1.f) cntf = 1.f;
    float pv = s / cntf;
    float p0 = pv * Wfc[c];
    float p1 = pv * Wfc[HC + c];
    #pragma unroll
    for (int off = 16; off >= 1; off >>= 1){
        p0 += __shfl_xor(p0, off);
        p1 += __shfl_xor(p1, off);
    }
    if (lane == 0){
        float l0 = p0 + bfc[0], l1 = p1 + bfc[1];
        float m = (l0 > l1) ? l0 : l1;
        float lse = m + logf(expf(l0 - m) + expf(l1 - m));
        out[g*2 + 0] = l0 - lse;
        out[g*2 + 1] = l1 - lse;
    }
}

extern "C" void kernel_launch(void* const* d_in, const int* in_sizes, int n_in,
                              void* d_out, int out_size, void* d_ws, size_t ws_size,
                              hipStream_t stream) {
    const int*   ei    = (const int*)  d_in[0];
    const int*   batch = (const int*)  d_in[1];
    const float* rnd   = (const float*)d_in[2];
    const float* W1l   = (const float*)d_in[3];
    const float* b1l   = (const float*)d_in[4];
    const float* W1r   = (const float*)d_in[5];
    const float* b1r   = (const float*)d_in[6];
    const float* att1  = (const float*)d_in[7];
    const float* bias1 = (const float*)d_in[8];
    const float* W2l   = (const float*)d_in[9];
    const float* b2l   = (const float*)d_in[10];
    const float* W2r   = (const float*)d_in[11];
    const float* b2r   = (const float*)d_in[12];
    const float* att2  = (const float*)d_in[13];
    const float* bias2 = (const float*)d_in[14];
    const float* Wfc   = (const float*)d_in[15];
    const float* bfc   = (const float*)d_in[16];

    const int E  = in_sizes[0] / 2;
    const int N  = in_sizes[1];
    const int G  = out_size / 2;
    const int EP = E + N;   // edges incl. self-loops

    // workspace layout
    float* ws    = (float*)d_ws;
    float* A     = ws;                        // N*HC
    float* B     = A + (size_t)N*HC;          // N*HC
    float* X     = B + (size_t)N*HC;          // N*HC
    unsigned* hist = (unsigned*)(X + (size_t)N*HC); // N
    int*   rsofs = (int*)hist + N;            // N+1
    int*   curs  = rsofs + N + 1;             // N
    int*   gb    = curs + N;                  // G+1
    int*   col   = gb + G + 1;                // EP

    const int T = 256;
    const int gNK = (N*HC + T-1)/T;
    const int gEP = (EP + T-1)/T;
    const int gSG = (N*2 + (T>>4) - 1)/(T>>4);   // 16 subgroups per 256-block

    hipMemsetAsync(hist, 0, (size_t)N*sizeof(unsigned), stream);

    // ---- degree/count histogram + CSR build (shared by both layers) ----
    k_hist <<<(E + T-1)/T, T, 0, stream>>>(ei, hist, E);
    k_scan <<<1, 1024, 0, stream>>>(hist, rsofs, N);
    hipMemcpyAsync(curs, rsofs, (size_t)N*sizeof(int), hipMemcpyDeviceToDevice, stream);
    k_scatter<<<gEP, T, 0, stream>>>(ei, E, EP, curs, col);
    k_bounds<<<(G + T)/T + 1, T, 0, stream>>>(batch, gb, N, G);

    // ---- layer 1 ----
    k_feat1<<<gNK, T, 0, stream>>>(hist, rnd, W1l, b1l, W1r, b1r, A, B, N);
    k_gat  <<<gSG, T, 0, stream>>>(rsofs, col, A, B, att1, bias1, X, N);

    // ---- layer 2 ----
    k_lin2 <<<gNK, T, 0, stream>>>(X, W2l, b2l, W2r, b2r, A, B, N);
    k_gat  <<<gSG, T, 0, stream>>>(rsofs, col, A, B, att2, bias2, X, N);

    // ---- fused pool + classifier (batch sorted -> contiguous ranges) ----
    k_poolfc<<<G, 64, 0, stream>>>(X, gb, Wfc, bfc, (float*)d_out, G);
}

// Round 4
// 411.109 us; speedup vs baseline: 15.4119x; 1.5835x over previous
//
#include <hip/hip_runtime.h>
#include <math.h>

#define HC 32      // H*C
#define CH 16      // channels per head
#define NSLOPE 0.2f
#define NEG_BIG -1e30f
#define NBMAX 256  // max coarse buckets (N <= 65536)
#define TILE 8192
#define CBMAX 12288

// entry i in [0, M): M = E (pairs) + N (self pairs) + E (src singletons)
// pair:      (dst<<16) | src
// self pair: (n<<16)   | n
// singleton: (src<<16) | 0xFFFF   (payload 0xFFFF is not a valid node id)
__device__ __forceinline__ unsigned gen_entry(const int* __restrict__ ei, int E, int EP, int i){
    if (i < E)       return (unsigned(ei[E+i]) << 16) | unsigned(ei[i]);
    if (i < EP){ unsigned n = i - E; return (n << 16) | n; }
    return (unsigned(ei[i-EP]) << 16) | 0xFFFFu;
}

// P1: coarse histogram (bucket = node >> 8), LDS-privatized
__global__ void k_p1(const int* __restrict__ ei, int E, int EP, int M,
                     unsigned* __restrict__ gPair, unsigned* __restrict__ gAll){
    __shared__ unsigned hp[NBMAX], hs[NBMAX];
    int t = threadIdx.x;
    hp[t] = 0; hs[t] = 0;
    __syncthreads();
    int stride = gridDim.x * blockDim.x;
    for (int i = blockIdx.x*blockDim.x + t; i < M; i += stride){
        unsigned e = gen_entry(ei, E, EP, i);
        unsigned b = e >> 24;
        if ((e & 0xFFFFu) == 0xFFFFu) atomicAdd(&hs[b], 1u);
        else                          atomicAdd(&hp[b], 1u);
    }
    __syncthreads();
    unsigned p = hp[t], a = p + hs[t];
    if (p) atomicAdd(&gPair[t], p);
    if (a) atomicAdd(&gAll[t],  a);
}

// scan over buckets: partition bases, col bases, P2 cursors; rs[N] = EP
__global__ void k_scan196(const unsigned* __restrict__ gPair, const unsigned* __restrict__ gAll,
                          int* __restrict__ partBase, int* __restrict__ colBase,
                          int* __restrict__ gcur, int* __restrict__ rsN, int EP, int nb){
    __shared__ int sp[NBMAX], sa[NBMAX];
    int t = threadIdx.x;
    int vp = (t < nb) ? (int)gPair[t] : 0;
    int va = (t < nb) ? (int)gAll[t]  : 0;
    sp[t] = vp; sa[t] = va;
    __syncthreads();
    for (int d = 1; d < NBMAX; d <<= 1){
        int xp = (t >= d) ? sp[t-d] : 0;
        int xa = (t >= d) ? sa[t-d] : 0;
        __syncthreads();
        sp[t] += xp; sa[t] += xa;
        __syncthreads();
    }
    if (t < nb){
        partBase[t] = sa[t] - va;
        colBase[t]  = sp[t] - vp;
        gcur[t]     = sa[t] - va;
    }
    if (t == 0) rsN[0] = EP;
}

// P2: per-tile LDS counting sort by coarse bucket, coalesced flush to partition buffer
__global__ void k_p2(const int* __restrict__ ei, int E, int EP, int M,
                     int* __restrict__ gcur, unsigned* __restrict__ part){
    __shared__ int bcnt[NBMAX], bstart[NBMAX], c2[NBMAX], gpos[NBMAX], sc[NBMAX];
    __shared__ unsigned sorted[TILE];
    __shared__ unsigned char bktof[TILE];
    int t = threadIdx.x;
    int base = blockIdx.x * TILE;
    int cnt = M - base; if (cnt > TILE) cnt = TILE;

    bcnt[t] = 0; c2[t] = 0;
    __syncthreads();
    for (int j = t; j < cnt; j += 256){
        unsigned e = gen_entry(ei, E, EP, base + j);
        atomicAdd(&bcnt[e >> 24], 1);
    }
    __syncthreads();
    int v = bcnt[t];
    sc[t] = v;
    __syncthreads();
    for (int d = 1; d < NBMAX; d <<= 1){
        int x = (t >= d) ? sc[t-d] : 0;
        __syncthreads();
        sc[t] += x;
        __syncthreads();
    }
    bstart[t] = sc[t] - v;
    if (v > 0){
        gpos[t] = atomicAdd(&gcur[t], v);
        int bs = bstart[t];
        for (int j = 0; j < v; ++j) bktof[bs + j] = (unsigned char)t;
    }
    __syncthreads();
    for (int j = t; j < cnt; j += 256){
        unsigned e = gen_entry(ei, E, EP, base + j);
        int b = e >> 24;
        int off = atomicAdd(&c2[b], 1);
        sorted[bstart[b] + off] = e;
    }
    __syncthreads();
    for (int k = t; k < cnt; k += 256){
        int b = bktof[k];
        part[gpos[b] + (k - bstart[b])] = sorted[k];
    }
}

// fine pass: one block per coarse bucket (256 nodes) -> rs, deg, col (all coalesced out)
__global__ void k_fine(const unsigned* __restrict__ part, const int* __restrict__ partBase,
                       const unsigned* __restrict__ gAll, const int* __restrict__ colBase,
                       int* __restrict__ rs, float* __restrict__ degf,
                       int* __restrict__ col, int N){
    __shared__ int pcnt[256], scnt[256], c2[256], lrs[257], sc[256];
    __shared__ int colbuf[CBMAX];
    int b = blockIdx.x, t = threadIdx.x;
    int beg = partBase[b], end = beg + (int)gAll[b];
    pcnt[t] = 0; scnt[t] = 0; c2[t] = 0;
    __syncthreads();
    for (int k = beg + t; k < end; k += 256){
        unsigned e = part[k];
        int j = (e >> 16) & 255;
        if ((e & 0xFFFFu) == 0xFFFFu) atomicAdd(&scnt[j], 1);
        else                          atomicAdd(&pcnt[j], 1);
    }
    __syncthreads();
    int v = pcnt[t];
    sc[t] = v;
    __syncthreads();
    for (int d = 1; d < 256; d <<= 1){
        int x = (t >= d) ? sc[t-d] : 0;
        __syncthreads();
        sc[t] += x;
        __syncthreads();
    }
    lrs[t] = sc[t] - v;
    if (t == 255) lrs[256] = sc[255];
    __syncthreads();
    int n = (b << 8) + t;
    if (n < N){
        rs[n]   = colBase[b] + lrs[t];
        degf[n] = (float)(pcnt[t] - 1 + scnt[t]);   // dstCnt + srcCnt over original edges
    }
    for (int k = beg + t; k < end; k += 256){
        unsigned e = part[k];
        if ((e & 0xFFFFu) == 0xFFFFu) continue;
        int j = (e >> 16) & 255;
        int pos = lrs[j] + atomicAdd(&c2[j], 1);
        if (pos < CBMAX) colbuf[pos] = (int)(e & 0xFFFFu);
    }
    __syncthreads();
    int npair = lrs[256];
    int cb = colBase[b];
    for (int k = t; k < npair; k += 256) col[cb + k] = colbuf[k];
}

// layer-1 xl/xr from features [1, deg, rand]
__global__ void k_feat1(const float* __restrict__ degf, const float* __restrict__ rnd,
                        const float* __restrict__ Wl, const float* __restrict__ bl,
                        const float* __restrict__ Wr, const float* __restrict__ br,
                        float* __restrict__ A, float* __restrict__ B, int N){
    int idx = blockIdx.x*blockDim.x + threadIdx.x;
    if (idx >= N*HC) return;
    int n = idx >> 5, k = idx & 31;
    float f1 = degf[n], f2 = rnd[n];
    A[idx] = Wl[k*3] + Wl[k*3+1]*f1 + Wl[k*3+2]*f2 + bl[k];
    B[idx] = Wr[k*3] + Wr[k*3+1]*f1 + Wr[k*3+2]*f2 + br[k];
}

// layer-2 xl/xr: two 32x32 linears sharing the x row
__global__ void k_lin2(const float* __restrict__ X,
                       const float* __restrict__ Wl, const float* __restrict__ bl,
                       const float* __restrict__ Wr, const float* __restrict__ br,
                       float* __restrict__ A, float* __restrict__ B, int N){
    int idx = blockIdx.x*blockDim.x + threadIdx.x;
    if (idx >= N*HC) return;
    int n = idx >> 5, k = idx & 31;
    const float* x  = X  + n*HC;
    const float* wl = Wl + k*HC;
    const float* wr = Wr + k*HC;
    float a = bl[k], b = br[k];
    #pragma unroll
    for (int j = 0; j < HC; ++j){ float xv = x[j]; a += xv*wl[j]; b += xv*wr[j]; }
    A[idx] = a; B[idx] = b;
}

// fused GATv2 layer: score + online softmax + aggregate + bias + ELU
__global__ void k_gat(const int* __restrict__ rs, const int* __restrict__ col,
                      const float* __restrict__ A, const float* __restrict__ B,
                      const float* __restrict__ att, const float* __restrict__ bias,
                      float* __restrict__ X, int N){
    int sg = blockIdx.x*(blockDim.x >> 4) + (threadIdx.x >> 4);
    int r  = threadIdx.x & 15;
    if (sg >= N*2) return;
    int d = sg >> 1, h = sg & 1;

    float xr[CH], at[CH];
    #pragma unroll
    for (int c = 0; c < CH; ++c){
        xr[c] = B[d*HC + h*CH + c];
        at[c] = att[h*CH + c];
    }

    float m = NEG_BIG, l = 0.f;
    float acc[CH];
    #pragma unroll
    for (int c = 0; c < CH; ++c) acc[c] = 0.f;

    int beg = rs[d], end = rs[d+1];
    for (int p = beg + r; p < end; p += 16){
        int s = col[p];
        const float* xl = A + s*HC + h*CH;
        float x[CH];
        #pragma unroll
        for (int c = 0; c < CH; ++c) x[c] = xl[c];
        float sc = 0.f;
        #pragma unroll
        for (int c = 0; c < CH; ++c){
            float mm = x[c] + xr[c];
            mm = (mm > 0.f) ? mm : NSLOPE*mm;
            sc += mm * at[c];
        }
        float nm = fmaxf(m, sc);
        float a  = __expf(m - nm);
        float p2 = __expf(sc - nm);
        l = l*a + p2;
        #pragma unroll
        for (int c = 0; c < CH; ++c) acc[c] = acc[c]*a + p2*x[c];
        m = nm;
    }

    #pragma unroll
    for (int off = 8; off >= 1; off >>= 1){
        float m2 = __shfl_xor(m, off);
        float l2 = __shfl_xor(l, off);
        float nm = fmaxf(m, m2);
        float a  = __expf(m  - nm);
        float b  = __expf(m2 - nm);
        l = l*a + l2*b;
        #pragma unroll
        for (int c = 0; c < CH; ++c)
            acc[c] = acc[c]*a + __shfl_xor(acc[c], off)*b;
        m = nm;
    }

    if (r == 0){
        float* o = X + d*HC + h*CH;
        #pragma unroll
        for (int c = 0; c < CH; ++c){
            float v = acc[c]/(l + 1e-16f) + bias[h*CH + c];
            o[c] = (v > 0.f) ? v : expm1f(v);
        }
    }
}

// batch is sorted: graph g's nodes are [gb[g], gb[g+1])
__global__ void k_bounds(const int* __restrict__ batch, int* __restrict__ gb, int N, int G){
    int g = blockIdx.x*blockDim.x + threadIdx.x;
    if (g > G) return;
    int lo = 0, hi = N;
    while (lo < hi){
        int mid = (lo + hi) >> 1;
        if (batch[mid] < g) lo = mid + 1; else hi = mid;
    }
    gb[g] = lo;
}

// fused mean-pool + fc + log_softmax: one 64-lane wave per graph
__global__ void k_poolfc(const float* __restrict__ X, const int* __restrict__ gb,
                         const float* __restrict__ Wfc, const float* __restrict__ bfc,
                         float* __restrict__ out, int G){
    int g = blockIdx.x;
    int lane = threadIdx.x;          // 64
    int c = lane & 31, half = lane >> 5;
    int beg = gb[g], end = gb[g+1];
    float s = 0.f;
    for (int n = beg + half; n < end; n += 2) s += X[n*HC + c];
    s += __shfl_xor(s, 32);
    float cntf = (float)(end - beg);
    if (cntf < 1.f) cntf = 1.f;
    float pv = s / cntf;
    float p0 = pv * Wfc[c];
    float p1 = pv * Wfc[HC + c];
    #pragma unroll
    for (int off = 16; off >= 1; off >>= 1){
        p0 += __shfl_xor(p0, off);
        p1 += __shfl_xor(p1, off);
    }
    if (lane == 0){
        float l0 = p0 + bfc[0], l1 = p1 + bfc[1];
        float m = (l0 > l1) ? l0 : l1;
        float lse = m + logf(expf(l0 - m) + expf(l1 - m));
        out[g*2 + 0] = l0 - lse;
        out[g*2 + 1] = l1 - lse;
    }
}

extern "C" void kernel_launch(void* const* d_in, const int* in_sizes, int n_in,
                              void* d_out, int out_size, void* d_ws, size_t ws_size,
                              hipStream_t stream) {
    const int*   ei    = (const int*)  d_in[0];
    const int*   batch = (const int*)  d_in[1];
    const float* rnd   = (const float*)d_in[2];
    const float* W1l   = (const float*)d_in[3];
    const float* b1l   = (const float*)d_in[4];
    const float* W1r   = (const float*)d_in[5];
    const float* b1r   = (const float*)d_in[6];
    const float* att1  = (const float*)d_in[7];
    const float* bias1 = (const float*)d_in[8];
    const float* W2l   = (const float*)d_in[9];
    const float* b2l   = (const float*)d_in[10];
    const float* W2r   = (const float*)d_in[11];
    const float* b2r   = (const float*)d_in[12];
    const float* att2  = (const float*)d_in[13];
    const float* bias2 = (const float*)d_in[14];
    const float* Wfc   = (const float*)d_in[15];
    const float* bfc   = (const float*)d_in[16];

    const int E  = in_sizes[0] / 2;
    const int N  = in_sizes[1];
    const int G  = out_size / 2;
    const int EP = E + N;        // pairs (edges + self-loops)
    const int M  = EP + E;       // + src singletons
    const int NB = (N + 255) >> 8;

    // workspace: part (13 MB) aliases A/B (dead until k_feat1, which runs after k_fine)
    float* ws    = (float*)d_ws;
    float* A     = ws;                          // N*HC
    float* B     = A + (size_t)N*HC;            // N*HC
    float* X     = B + (size_t)N*HC;            // N*HC
    unsigned* part = (unsigned*)ws;             // M u32 (aliases A,B, head of X)
    float* degf  = X + (size_t)N*HC;            // N
    int*   rs    = (int*)(degf + N);            // N+1
    int*   col   = rs + N + 1;                  // EP
    unsigned* gPair = (unsigned*)(col + EP);    // NB
    unsigned* gAll  = gPair + NBMAX;            // NB
    int*   partBase = (int*)(gAll + NBMAX);     // NB
    int*   colBase  = partBase + NBMAX;         // NB
    int*   gcur     = colBase + NBMAX;          // NB
    int*   gb       = gcur + NBMAX;             // G+1

    const int T = 256;
    const int gNK = (N*HC + T-1)/T;
    const int gSG = (N*2 + (T>>4) - 1)/(T>>4);
    const int nTiles = (M + TILE - 1)/TILE;

    hipMemsetAsync(gPair, 0, 2*NBMAX*sizeof(unsigned), stream);

    // ---- CSR + degree build: two-level LDS counting sort, no global data atomics ----
    k_p1     <<<256, T, 0, stream>>>(ei, E, EP, M, gPair, gAll);
    k_scan196<<<1, NBMAX, 0, stream>>>(gPair, gAll, partBase, colBase, gcur, rs + N, EP, NB);
    k_p2     <<<nTiles, T, 0, stream>>>(ei, E, EP, M, gcur, part);
    k_fine   <<<NB, T, 0, stream>>>(part, partBase, gAll, colBase, rs, degf, col, N);
    k_bounds <<<(G + T)/T + 1, T, 0, stream>>>(batch, gb, N, G);

    // ---- layer 1 ----
    k_feat1<<<gNK, T, 0, stream>>>(degf, rnd, W1l, b1l, W1r, b1r, A, B, N);
    k_gat  <<<gSG, T, 0, stream>>>(rs, col, A, B, att1, bias1, X, N);

    // ---- layer 2 ----
    k_lin2 <<<gNK, T, 0, stream>>>(X, W2l, b2l, W2r, b2r, A, B, N);
    k_gat  <<<gSG, T, 0, stream>>>(rs, col, A, B, att2, bias2, X, N);

    // ---- fused pool + classifier ----
    k_poolfc<<<G, 64, 0, stream>>>(X, gb, Wfc, bfc, (float*)d_out, G);
}

// Round 5
// 385.370 us; speedup vs baseline: 16.4413x; 1.0668x over previous
//
#include <hip/hip_runtime.h>
#include <math.h>

#define HC 32      // H*C
#define CH 16      // channels per head
#define NSLOPE 0.2f
#define NEG_BIG -1e30f
#define NBMAX 256  // max coarse buckets (N <= 65536)
#define TILE 8192
#define CBMAX 12288

// entry i in [0, M): M = E (pairs) + N (self pairs) + E (src singletons)
// pair:      (dst<<16) | src
// self pair: (n<<16)   | n
// singleton: (src<<16) | 0xFFFF   (payload 0xFFFF is not a valid node id)
__device__ __forceinline__ unsigned gen_entry(const int* __restrict__ ei, int E, int EP, int i){
    if (i < E)       return (unsigned(ei[E+i]) << 16) | unsigned(ei[i]);
    if (i < EP){ unsigned n = i - E; return (n << 16) | n; }
    return (unsigned(ei[i-EP]) << 16) | 0xFFFFu;
}

// P1: coarse histogram (bucket = node >> 8), LDS-privatized
__global__ void k_p1(const int* __restrict__ ei, int E, int EP, int M,
                     unsigned* __restrict__ gPair, unsigned* __restrict__ gAll){
    __shared__ unsigned hp[NBMAX], hs[NBMAX];
    int t = threadIdx.x;
    hp[t] = 0; hs[t] = 0;
    __syncthreads();
    int stride = gridDim.x * blockDim.x;
    for (int i = blockIdx.x*blockDim.x + t; i < M; i += stride){
        unsigned e = gen_entry(ei, E, EP, i);
        unsigned b = e >> 24;
        if ((e & 0xFFFFu) == 0xFFFFu) atomicAdd(&hs[b], 1u);
        else                          atomicAdd(&hp[b], 1u);
    }
    __syncthreads();
    unsigned p = hp[t], a = p + hs[t];
    if (p) atomicAdd(&gPair[t], p);
    if (a) atomicAdd(&gAll[t],  a);
}

// scan over buckets: partition bases, col bases, P2 cursors; rs[N] = EP
__global__ void k_scan196(const unsigned* __restrict__ gPair, const unsigned* __restrict__ gAll,
                          int* __restrict__ partBase, int* __restrict__ colBase,
                          int* __restrict__ gcur, int* __restrict__ rsN, int EP, int nb){
    __shared__ int sp[NBMAX], sa[NBMAX];
    int t = threadIdx.x;
    int vp = (t < nb) ? (int)gPair[t] : 0;
    int va = (t < nb) ? (int)gAll[t]  : 0;
    sp[t] = vp; sa[t] = va;
    __syncthreads();
    for (int d = 1; d < NBMAX; d <<= 1){
        int xp = (t >= d) ? sp[t-d] : 0;
        int xa = (t >= d) ? sa[t-d] : 0;
        __syncthreads();
        sp[t] += xp; sa[t] += xa;
        __syncthreads();
    }
    if (t < nb){
        partBase[t] = sa[t] - va;
        colBase[t]  = sp[t] - vp;
        gcur[t]     = sa[t] - va;
    }
    if (t == 0) rsN[0] = EP;
}

// P2: per-tile LDS counting sort by coarse bucket, coalesced flush to partition buffer
__global__ void k_p2(const int* __restrict__ ei, int E, int EP, int M,
                     int* __restrict__ gcur, unsigned* __restrict__ part){
    __shared__ int bcnt[NBMAX], bstart[NBMAX], c2[NBMAX], gpos[NBMAX], sc[NBMAX];
    __shared__ unsigned sorted[TILE];
    __shared__ unsigned char bktof[TILE];
    int t = threadIdx.x;
    int base = blockIdx.x * TILE;
    int cnt = M - base; if (cnt > TILE) cnt = TILE;

    bcnt[t] = 0; c2[t] = 0;
    __syncthreads();
    for (int j = t; j < cnt; j += 256){
        unsigned e = gen_entry(ei, E, EP, base + j);
        atomicAdd(&bcnt[e >> 24], 1);
    }
    __syncthreads();
    int v = bcnt[t];
    sc[t] = v;
    __syncthreads();
    for (int d = 1; d < NBMAX; d <<= 1){
        int x = (t >= d) ? sc[t-d] : 0;
        __syncthreads();
        sc[t] += x;
        __syncthreads();
    }
    bstart[t] = sc[t] - v;
    if (v > 0){
        gpos[t] = atomicAdd(&gcur[t], v);
        int bs = bstart[t];
        for (int j = 0; j < v; ++j) bktof[bs + j] = (unsigned char)t;
    }
    __syncthreads();
    for (int j = t; j < cnt; j += 256){
        unsigned e = gen_entry(ei, E, EP, base + j);
        int b = e >> 24;
        int off = atomicAdd(&c2[b], 1);
        sorted[bstart[b] + off] = e;
    }
    __syncthreads();
    for (int k = t; k < cnt; k += 256){
        int b = bktof[k];
        part[gpos[b] + (k - bstart[b])] = sorted[k];
    }
}

// fine pass: one block per coarse bucket (256 nodes) -> rs, (deg,rnd) pack, col
__global__ void k_fine(const unsigned* __restrict__ part, const int* __restrict__ partBase,
                       const unsigned* __restrict__ gAll, const int* __restrict__ colBase,
                       const float* __restrict__ rnd,
                       int* __restrict__ rs, float2* __restrict__ dr,
                       int* __restrict__ col, int N){
    __shared__ int pcnt[256], scnt[256], c2[256], lrs[257], sc[256];
    __shared__ int colbuf[CBMAX];
    int b = blockIdx.x, t = threadIdx.x;
    int beg = partBase[b], end = beg + (int)gAll[b];
    pcnt[t] = 0; scnt[t] = 0; c2[t] = 0;
    __syncthreads();
    for (int k = beg + t; k < end; k += 256){
        unsigned e = part[k];
        int j = (e >> 16) & 255;
        if ((e & 0xFFFFu) == 0xFFFFu) atomicAdd(&scnt[j], 1);
        else                          atomicAdd(&pcnt[j], 1);
    }
    __syncthreads();
    int v = pcnt[t];
    sc[t] = v;
    __syncthreads();
    for (int d = 1; d < 256; d <<= 1){
        int x = (t >= d) ? sc[t-d] : 0;
        __syncthreads();
        sc[t] += x;
        __syncthreads();
    }
    lrs[t] = sc[t] - v;
    if (t == 255) lrs[256] = sc[255];
    __syncthreads();
    int n = (b << 8) + t;
    if (n < N){
        rs[n] = colBase[b] + lrs[t];
        dr[n] = make_float2((float)(pcnt[t] - 1 + scnt[t]), rnd[n]);  // deg, rand
    }
    for (int k = beg + t; k < end; k += 256){
        unsigned e = part[k];
        if ((e & 0xFFFFu) == 0xFFFFu) continue;
        int j = (e >> 16) & 255;
        int pos = lrs[j] + atomicAdd(&c2[j], 1);
        if (pos < CBMAX) colbuf[pos] = (int)(e & 0xFFFFu);
    }
    __syncthreads();
    int npair = lrs[256];
    int cb = colBase[b];
    for (int k = t; k < npair; k += 256) col[cb + k] = colbuf[k];
}

// pack layer-1 weights: tabA[k]=(Wl0+bl, Wl1, Wl2, att), tabB[k]=(Wr0+br, Wr1, Wr2, bias)
__global__ void k_prep(const float* __restrict__ Wl, const float* __restrict__ bl,
                       const float* __restrict__ Wr, const float* __restrict__ br,
                       const float* __restrict__ att, const float* __restrict__ bias,
                       float4* __restrict__ tabA, float4* __restrict__ tabB){
    int k = threadIdx.x;
    if (k >= HC) return;
    tabA[k] = make_float4(Wl[k*3] + bl[k], Wl[k*3+1], Wl[k*3+2], att[k]);
    tabB[k] = make_float4(Wr[k*3] + br[k], Wr[k*3+1], Wr[k*3+2], bias[k]);
}

// fused layer-1 GATv2: rank-3 features -> 8 B gather + 4-scalar online softmax.
// xl[s][c] = ul[c] + v[c]*deg_s + w[c]*rnd_s  =>  sum(alpha*xl) = ul + (v*S1 + w*S2)/l
__global__ void k_gat1(const int* __restrict__ rs, const int* __restrict__ col,
                       const float2* __restrict__ dr,
                       const float4* __restrict__ tabA, const float4* __restrict__ tabB,
                       float* __restrict__ X, int N){
    int sg = blockIdx.x*(blockDim.x >> 3) + (threadIdx.x >> 3);
    int r  = threadIdx.x & 7;
    if (sg >= N*2) return;
    int d = sg >> 1, h = sg & 1;

    float2 drd = dr[d];
    float base[CH], v[CH], w[CH], at[CH];
    #pragma unroll
    for (int c = 0; c < CH; ++c){
        float4 a4 = tabA[h*CH + c];
        float4 b4 = tabB[h*CH + c];
        float xr = b4.x + b4.y*drd.x + b4.z*drd.y;
        base[c] = a4.x + xr; v[c] = a4.y; w[c] = a4.z; at[c] = a4.w;
    }

    float m = NEG_BIG, l = 0.f, S1 = 0.f, S2 = 0.f;
    int beg = rs[d], end = rs[d+1];
    for (int p = beg + r; p < end; p += 8){
        float2 ds = dr[col[p]];
        float sc = 0.f;
        #pragma unroll
        for (int c = 0; c < CH; ++c){
            float mm = base[c] + v[c]*ds.x + w[c]*ds.y;
            mm = (mm > 0.f) ? mm : NSLOPE*mm;
            sc += mm * at[c];
        }
        float nm = fmaxf(m, sc);
        float a  = __expf(m - nm);
        float p2 = __expf(sc - nm);
        l  = l*a  + p2;
        S1 = S1*a + p2*ds.x;
        S2 = S2*a + p2*ds.y;
        m = nm;
    }

    #pragma unroll
    for (int off = 4; off >= 1; off >>= 1){
        float m2 = __shfl_xor(m, off);
        float l2 = __shfl_xor(l, off);
        float t1 = __shfl_xor(S1, off);
        float t2 = __shfl_xor(S2, off);
        float nm = fmaxf(m, m2);
        float a  = __expf(m  - nm);
        float b  = __expf(m2 - nm);
        l  = l*a  + l2*b;
        S1 = S1*a + t1*b;
        S2 = S2*a + t2*b;
        m = nm;
    }

    if (r == 0){
        float invl = 1.f/(l + 1e-16f);
        float* o = X + d*HC + h*CH;
        #pragma unroll
        for (int c = 0; c < CH; ++c){
            float4 a4 = tabA[h*CH + c];
            float4 b4 = tabB[h*CH + c];
            float val = a4.x + (a4.y*S1 + a4.z*S2)*invl + b4.w;
            o[c] = (val > 0.f) ? val : expm1f(val);
        }
    }
}

// layer-2 xl/xr: two 32x32 linears sharing the x row
__global__ void k_lin2(const float* __restrict__ X,
                       const float* __restrict__ Wl, const float* __restrict__ bl,
                       const float* __restrict__ Wr, const float* __restrict__ br,
                       float* __restrict__ A, float* __restrict__ B, int N){
    int idx = blockIdx.x*blockDim.x + threadIdx.x;
    if (idx >= N*HC) return;
    int n = idx >> 5, k = idx & 31;
    const float* x  = X  + n*HC;
    const float* wl = Wl + k*HC;
    const float* wr = Wr + k*HC;
    float a = bl[k], b = br[k];
    #pragma unroll
    for (int j = 0; j < HC; ++j){ float xv = x[j]; a += xv*wl[j]; b += xv*wr[j]; }
    A[idx] = a; B[idx] = b;
}

// fused layer-2 GATv2: score + online softmax + aggregate + bias + ELU (16-lane subgroups)
__global__ void k_gat(const int* __restrict__ rs, const int* __restrict__ col,
                      const float* __restrict__ A, const float* __restrict__ B,
                      const float* __restrict__ att, const float* __restrict__ bias,
                      float* __restrict__ X, int N){
    int sg = blockIdx.x*(blockDim.x >> 4) + (threadIdx.x >> 4);
    int r  = threadIdx.x & 15;
    if (sg >= N*2) return;
    int d = sg >> 1, h = sg & 1;

    float xr[CH], at[CH];
    #pragma unroll
    for (int c = 0; c < CH; ++c){
        xr[c] = B[d*HC + h*CH + c];
        at[c] = att[h*CH + c];
    }

    float m = NEG_BIG, l = 0.f;
    float acc[CH];
    #pragma unroll
    for (int c = 0; c < CH; ++c) acc[c] = 0.f;

    int beg = rs[d], end = rs[d+1];
    for (int p = beg + r; p < end; p += 16){
        int s = col[p];
        const float* xl = A + s*HC + h*CH;
        float x[CH];
        #pragma unroll
        for (int c = 0; c < CH; ++c) x[c] = xl[c];
        float sc = 0.f;
        #pragma unroll
        for (int c = 0; c < CH; ++c){
            float mm = x[c] + xr[c];
            mm = (mm > 0.f) ? mm : NSLOPE*mm;
            sc += mm * at[c];
        }
        float nm = fmaxf(m, sc);
        float a  = __expf(m - nm);
        float p2 = __expf(sc - nm);
        l = l*a + p2;
        #pragma unroll
        for (int c = 0; c < CH; ++c) acc[c] = acc[c]*a + p2*x[c];
        m = nm;
    }

    #pragma unroll
    for (int off = 8; off >= 1; off >>= 1){
        float m2 = __shfl_xor(m, off);
        float l2 = __shfl_xor(l, off);
        float nm = fmaxf(m, m2);
        float a  = __expf(m  - nm);
        float b  = __expf(m2 - nm);
        l = l*a + l2*b;
        #pragma unroll
        for (int c = 0; c < CH; ++c)
            acc[c] = acc[c]*a + __shfl_xor(acc[c], off)*b;
        m = nm;
    }

    if (r == 0){
        float* o = X + d*HC + h*CH;
        #pragma unroll
        for (int c = 0; c < CH; ++c){
            float v = acc[c]/(l + 1e-16f) + bias[h*CH + c];
            o[c] = (v > 0.f) ? v : expm1f(v);
        }
    }
}

// batch is sorted: graph g's nodes are [gb[g], gb[g+1])
__global__ void k_bounds(const int* __restrict__ batch, int* __restrict__ gb, int N, int G){
    int g = blockIdx.x*blockDim.x + threadIdx.x;
    if (g > G) return;
    int lo = 0, hi = N;
    while (lo < hi){
        int mid = (lo + hi) >> 1;
        if (batch[mid] < g) lo = mid + 1; else hi = mid;
    }
    gb[g] = lo;
}

// fused mean-pool + fc + log_softmax: one 64-lane wave per graph
__global__ void k_poolfc(const float* __restrict__ X, const int* __restrict__ gb,
                         const float* __restrict__ Wfc, const float* __restrict__ bfc,
                         float* __restrict__ out, int G){
    int g = blockIdx.x;
    int lane = threadIdx.x;          // 64
    int c = lane & 31, half = lane >> 5;
    int beg = gb[g], end = gb[g+1];
    float s = 0.f;
    for (int n = beg + half; n < end; n += 2) s += X[n*HC + c];
    s += __shfl_xor(s, 32);
    float cntf = (float)(end - beg);
    if (cntf < 1.f) cntf = 1.f;
    float pv = s / cntf;
    float p0 = pv * Wfc[c];
    float p1 = pv * Wfc[HC + c];
    #pragma unroll
    for (int off = 16; off >= 1; off >>= 1){
        p0 += __shfl_xor(p0, off);
        p1 += __shfl_xor(p1, off);
    }
    if (lane == 0){
        float l0 = p0 + bfc[0], l1 = p1 + bfc[1];
        float m = (l0 > l1) ? l0 : l1;
        float lse = m + logf(expf(l0 - m) + expf(l1 - m));
        out[g*2 + 0] = l0 - lse;
        out[g*2 + 1] = l1 - lse;
    }
}

extern "C" void kernel_launch(void* const* d_in, const int* in_sizes, int n_in,
                              void* d_out, int out_size, void* d_ws, size_t ws_size,
                              hipStream_t stream) {
    const int*   ei    = (const int*)  d_in[0];
    const int*   batch = (const int*)  d_in[1];
    const float* rnd   = (const float*)d_in[2];
    const float* W1l   = (const float*)d_in[3];
    const float* b1l   = (const float*)d_in[4];
    const float* W1r   = (const float*)d_in[5];
    const float* b1r   = (const float*)d_in[6];
    const float* att1  = (const float*)d_in[7];
    const float* bias1 = (const float*)d_in[8];
    const float* W2l   = (const float*)d_in[9];
    const float* b2l   = (const float*)d_in[10];
    const float* W2r   = (const float*)d_in[11];
    const float* b2r   = (const float*)d_in[12];
    const float* att2  = (const float*)d_in[13];
    const float* bias2 = (const float*)d_in[14];
    const float* Wfc   = (const float*)d_in[15];
    const float* bfc   = (const float*)d_in[16];

    const int E  = in_sizes[0] / 2;
    const int N  = in_sizes[1];
    const int G  = out_size / 2;
    const int EP = E + N;        // pairs (edges + self-loops)
    const int M  = EP + E;       // + src singletons
    const int NB = (N + 255) >> 8;

    // workspace: part (13 MB) aliases A/B/X-head (dead until after k_fine)
    float* ws    = (float*)d_ws;
    float* A     = ws;                          // N*HC
    float* B     = A + (size_t)N*HC;            // N*HC
    float* X     = B + (size_t)N*HC;            // N*HC
    unsigned* part = (unsigned*)ws;             // M u32 (aliases A,B, head of X)
    float2* dr   = (float2*)(X + (size_t)N*HC); // N float2 (deg, rnd)
    int*   rs    = (int*)(dr + N);              // N+1
    int*   col   = rs + N + 1;                  // EP
    unsigned* gPair = (unsigned*)(col + EP);    // NB
    unsigned* gAll  = gPair + NBMAX;            // NB
    int*   partBase = (int*)(gAll + NBMAX);     // NB
    int*   colBase  = partBase + NBMAX;         // NB
    int*   gcur     = colBase + NBMAX;          // NB
    int*   gb       = gcur + NBMAX;             // G+1
    float4* tabA    = (float4*)(gb + G + 2);    // HC (align up: G+1 -> +2 keeps 16B align? ensure below)
    // ensure 16-byte alignment for float4 tables
    tabA = (float4*)((((size_t)(gb + G + 1)) + 15) & ~(size_t)15);
    float4* tabB    = tabA + HC;

    const int T = 256;
    const int gNK = (N*HC + T-1)/T;
    const int gS8 = (N*2 + (T>>3) - 1)/(T>>3);   // 8-lane subgroups (layer 1)
    const int gS16= (N*2 + (T>>4) - 1)/(T>>4);   // 16-lane subgroups (layer 2)
    const int nTiles = (M + TILE - 1)/TILE;

    hipMemsetAsync(gPair, 0, 2*NBMAX*sizeof(unsigned), stream);

    // ---- CSR + (deg,rnd) build: two-level LDS counting sort ----
    k_prep   <<<1, 64, 0, stream>>>(W1l, b1l, W1r, b1r, att1, bias1, tabA, tabB);
    k_p1     <<<256, T, 0, stream>>>(ei, E, EP, M, gPair, gAll);
    k_scan196<<<1, NBMAX, 0, stream>>>(gPair, gAll, partBase, colBase, gcur, rs + N, EP, NB);
    k_p2     <<<nTiles, T, 0, stream>>>(ei, E, EP, M, gcur, part);
    k_fine   <<<NB, T, 0, stream>>>(part, partBase, gAll, colBase, rnd, rs, dr, col, N);
    k_bounds <<<(G + T)/T + 1, T, 0, stream>>>(batch, gb, N, G);

    // ---- layer 1 (on-the-fly features, 8 B gathers, 4-scalar softmax state) ----
    k_gat1<<<gS8, T, 0, stream>>>(rs, col, dr, tabA, tabB, X, N);

    // ---- layer 2 ----
    k_lin2<<<gNK, T, 0, stream>>>(X, W2l, b2l, W2r, b2r, A, B, N);
    k_gat <<<gS16, T, 0, stream>>>(rs, col, A, B, att2, bias2, X, N);

    // ---- fused pool + classifier ----
    k_poolfc<<<G, 64, 0, stream>>>(X, gb, Wfc, bfc, (float*)d_out, G);
}